// Round 3
// baseline (586.031 us; speedup 1.0000x reference)
//
#include <hip/hip_runtime.h>
#include <hip/hip_bf16.h>

// Problem constants (from reference setup_inputs)
#define F_SIZE 1024
#define E_DIM  128
#define N_D    6000
#define N_SE   1000
#define N_TOT  7000
#define M_TPL  300000
#define LAMB   1e-6f
#define KPAD   7040   // N_TOT rounded up (xT / A16 leading dim)

typedef __bf16 bf16x8 __attribute__((ext_vector_type(8)));
typedef float  f32x4  __attribute__((ext_vector_type(4)));

__device__ __forceinline__ float hshrink(float v) {
    return fabsf(v) > LAMB ? v : 0.0f;
}

// RNE float -> bf16 bits (inputs are finite; no NaN handling needed)
__device__ __forceinline__ unsigned short f2bf(float f) {
    unsigned int u = __builtin_bit_cast(unsigned int, f);
    unsigned int r = u + 0x7fffu + ((u >> 16) & 1u);
    return (unsigned short)(r >> 16);
}

// ---------------------------------------------------------------------------
// Small GEMM (K=128) fusing the split-K reduction of its fp32 A input.
//   Ain[r][k] = pre( sum_s parts[s][r][k] )   pre: optional +preBias then relu
//   out[r][e] = act( Ain@W + bias )           act: 0=relu 1=hardshrink
// ---------------------------------------------------------------------------
__global__ __launch_bounds__(256) void gemm_small(const float* __restrict__ parts,
                                                  int nparts, size_t partStride,
                                                  const float* __restrict__ preBias,
                                                  const float* __restrict__ W,
                                                  const float* __restrict__ bias,
                                                  float* __restrict__ outp,
                                                  int Mrows, int act) {
    constexpr int BM = 64, BN = 128, BK = 16, KD = 128;
    __shared__ float As[BK][BM];
    __shared__ float Bs[BK][BN];

    const int tid = threadIdx.x;
    const int tn  = tid & 31;
    const int tm  = tid >> 5;
    const int row0 = blockIdx.x * BM;

    float acc[8][4];
#pragma unroll
    for (int i = 0; i < 8; i++)
#pragma unroll
        for (int j = 0; j < 4; j++) acc[i][j] = 0.0f;

    const int lr = tid >> 2;
    const int lk = (tid & 3) * 4;
    const int grow = row0 + lr;

    for (int kt = 0; kt < KD / BK; kt++) {
        const int k0 = kt * BK;
        __syncthreads();
        float4 av = make_float4(0.f, 0.f, 0.f, 0.f);
        if (grow < Mrows) {
            for (int s = 0; s < nparts; s++) {
                float4 p = *(const float4*)(parts + (size_t)s * partStride +
                                            (size_t)grow * KD + (k0 + lk));
                av.x += p.x; av.y += p.y; av.z += p.z; av.w += p.w;
            }
            if (preBias != nullptr) {
                float4 pb = *(const float4*)(preBias + k0 + lk);
                av.x = fmaxf(av.x + pb.x, 0.f);
                av.y = fmaxf(av.y + pb.y, 0.f);
                av.z = fmaxf(av.z + pb.z, 0.f);
                av.w = fmaxf(av.w + pb.w, 0.f);
            }
        }
        As[lk + 0][lr] = av.x;
        As[lk + 1][lr] = av.y;
        As[lk + 2][lr] = av.z;
        As[lk + 3][lr] = av.w;
        {
            int f  = tid;
            int bk = f >> 5, bn = (f & 31) * 4;
            *(float4*)&Bs[bk][bn] = *(const float4*)(W + (size_t)(k0 + bk) * BN + bn);
            f  = tid + 256;
            bk = f >> 5; bn = (f & 31) * 4;
            *(float4*)&Bs[bk][bn] = *(const float4*)(W + (size_t)(k0 + bk) * BN + bn);
        }
        __syncthreads();
#pragma unroll
        for (int k = 0; k < BK; k++) {
            float4 a0 = *(const float4*)&As[k][tm * 8];
            float4 a1 = *(const float4*)&As[k][tm * 8 + 4];
            float4 bv = *(const float4*)&Bs[k][tn * 4];
            float a[8] = {a0.x, a0.y, a0.z, a0.w, a1.x, a1.y, a1.z, a1.w};
            float b[4] = {bv.x, bv.y, bv.z, bv.w};
#pragma unroll
            for (int i = 0; i < 8; i++)
#pragma unroll
                for (int j = 0; j < 4; j++) acc[i][j] += a[i] * b[j];
        }
    }

    float4 bv = *(const float4*)(bias + tn * 4);
    float bb[4] = {bv.x, bv.y, bv.z, bv.w};
#pragma unroll
    for (int i = 0; i < 8; i++) {
        int r = row0 + tm * 8 + i;
        if (r < Mrows) {
            float v[4];
#pragma unroll
            for (int j = 0; j < 4; j++) {
                float u = acc[i][j] + bb[j];
                v[j] = act == 0 ? fmaxf(u, 0.f) : hshrink(u);
            }
            *(float4*)(outp + (size_t)r * BN + tn * 4) =
                make_float4(v[0], v[1], v[2], v[3]);
        }
    }
}

// ---------------------------------------------------------------------------
__global__ void emb_copy(const float* __restrict__ embSe, float* __restrict__ x) {
    int i = blockIdx.x * blockDim.x + threadIdx.x;
    if (i < N_SE * E_DIM / 4)
        ((float4*)(x + (size_t)N_D * E_DIM))[i] = ((const float4*)embSe)[i];
}

// ---------------------------------------------------------------------------
// src [nrows][128] fp32 -> dst [128][kpad] bf16 (rows >= nrows zero-filled)
// grid: (kpad/64, 2)
// ---------------------------------------------------------------------------
__global__ __launch_bounds__(256) void transpose_bf16(const float* __restrict__ src,
                                                      unsigned short* __restrict__ dst,
                                                      int nrows, int kpad) {
    __shared__ float t[64][65];
    const int r0 = blockIdx.x * 64;
    const int c0 = blockIdx.y * 64;
    const int tid = threadIdx.x;
    {
        const int i  = tid >> 4;          // 0..15
        const int cq = (tid & 15) * 4;
#pragma unroll
        for (int j = 0; j < 4; j++) {
            int r = r0 + i + j * 16;
            float4 v = make_float4(0.f, 0.f, 0.f, 0.f);
            if (r < nrows) v = *(const float4*)(src + (size_t)r * E_DIM + c0 + cq);
            t[i + j * 16][cq + 0] = v.x;
            t[i + j * 16][cq + 1] = v.y;
            t[i + j * 16][cq + 2] = v.z;
            t[i + j * 16][cq + 3] = v.w;
        }
    }
    __syncthreads();
    {
        const int ci = tid >> 2;          // 0..63
        const int rq = (tid & 3) * 16;
        unsigned short us[16];
#pragma unroll
        for (int j = 0; j < 16; j++) us[j] = f2bf(t[rq + j][ci]);
        unsigned short* dp = dst + (size_t)(c0 + ci) * kpad + r0 + rq;
        *(uint4*)dp       = *(uint4*)&us[0];
        *(uint4*)(dp + 8) = *(uint4*)&us[8];
    }
}

// ---------------------------------------------------------------------------
// xs[r][e] = bf16( x[r][e] * rsd[r] )  — pre-scaled gather source for the head
// ---------------------------------------------------------------------------
__global__ __launch_bounds__(256) void scale_x_bf16(const float* __restrict__ x,
                                                    const float* __restrict__ rsd,
                                                    unsigned short* __restrict__ xs) {
    int t = blockIdx.x * 256 + threadIdx.x;    // one thread per 8 elements
    if (t < N_TOT * (E_DIM / 8)) {
        int r = t >> 4;
        int c = (t & 15) * 8;
        float sc = rsd[r];
        const float* sp = x + (size_t)r * E_DIM + c;
        float4 v0 = *(const float4*)sp;
        float4 v1 = *(const float4*)(sp + 4);
        unsigned short us[8];
        us[0] = f2bf(v0.x * sc); us[1] = f2bf(v0.y * sc);
        us[2] = f2bf(v0.z * sc); us[3] = f2bf(v0.w * sc);
        us[4] = f2bf(v1.x * sc); us[5] = f2bf(v1.y * sc);
        us[6] = f2bf(v1.z * sc); us[7] = f2bf(v1.w * sc);
        *(uint4*)(xs + (size_t)r * E_DIM + c) = *(uint4*)us;
    }
}

// ---------------------------------------------------------------------------
// bf16 MFMA split-K GEMM:  Cpart[sp][row][n] = sum_{k chunk} A[row][k]*BT[n][k]
// MODE 0: A fp32, cvt during staging.
// MODE 1: A fp32, cvt during staging AND write bf16 tiles to A16 (each element
//         covered exactly once by the split-K grid).
// MODE 2: read pre-converted bf16 A16.
// 128x128 tile, BK=32, 4 waves x 4x4 16x16x32 MFMAs. LDS rows padded to 40
// bf16 (80 B) -> 2-way bank aliasing only (free).
// ---------------------------------------------------------------------------
template <int MODE>
__global__ __launch_bounds__(256) void gemm_bf16(const float* __restrict__ A, int lda,
                                                 unsigned short* __restrict__ A16, int lda16,
                                                 const unsigned short* __restrict__ BT, int ldbt,
                                                 float* __restrict__ Cpart,
                                                 int M, int K) {
    __shared__ unsigned short As[128 * 40];
    __shared__ unsigned short Bs[128 * 40];

    const int tid = threadIdx.x;
    const int row0 = blockIdx.x * 128;
    const int sp = blockIdx.y, nsp = gridDim.y;
    const int KT = (K + 31) / 32;
    const int kt0 = (sp * KT) / nsp;
    const int kt1 = ((sp + 1) * KT) / nsp;

    const int mrow = tid >> 1;                      // 0..127
    const int kq   = (tid & 1) * 16;                // 0 or 16
    const bool mok = (row0 + mrow) < M;

    const int lane = tid & 63;
    const int w  = tid >> 6;
    const int wm = (w & 1) * 64;
    const int wn = (w >> 1) * 64;
    const int fm = lane & 15;
    const int ko = (lane >> 4) * 8;

    const f32x4 zero = {0.f, 0.f, 0.f, 0.f};
    f32x4 acc[4][4];
#pragma unroll
    for (int i = 0; i < 4; i++)
#pragma unroll
        for (int j = 0; j < 4; j++) acc[i][j] = zero;

    for (int kt = kt0; kt < kt1; kt++) {
        const int k0 = kt * 32;
        __syncthreads();
        // ---- A tile -> As[m][k] ----
        if (MODE == 2) {
            uint4 b0 = make_uint4(0, 0, 0, 0), b1 = b0;
            if (mok) {
                const uint4* src = (const uint4*)(A16 + (size_t)(row0 + mrow) * lda16 + k0 + kq);
                b0 = src[0];
                b1 = src[1];
            }
            *(uint4*)&As[mrow * 40 + kq]     = b0;
            *(uint4*)&As[mrow * 40 + kq + 8] = b1;
        } else {
            unsigned short us[16];
            const float* aBase = A + (size_t)(row0 + mrow) * lda;
#pragma unroll
            for (int j = 0; j < 4; j++) {
                float4 v = make_float4(0.f, 0.f, 0.f, 0.f);
                int k = k0 + kq + 4 * j;
                if (mok && k < K) v = *(const float4*)(aBase + k);
                us[4 * j + 0] = f2bf(v.x);
                us[4 * j + 1] = f2bf(v.y);
                us[4 * j + 2] = f2bf(v.z);
                us[4 * j + 3] = f2bf(v.w);
            }
            *(uint4*)&As[mrow * 40 + kq]     = *(uint4*)&us[0];
            *(uint4*)&As[mrow * 40 + kq + 8] = *(uint4*)&us[8];
            if (MODE == 1 && mok) {
                uint4* dp = (uint4*)(A16 + (size_t)(row0 + mrow) * lda16 + k0 + kq);
                dp[0] = *(uint4*)&us[0];
                dp[1] = *(uint4*)&us[8];
            }
        }
        // ---- B tile: bf16 copy BT[n][k0..k0+32) -> Bs[n][k] ----
        {
            const uint4* src = (const uint4*)(BT + (size_t)mrow * ldbt + k0 + kq);
            uint4 b0 = src[0];
            uint4 b1 = src[1];
            *(uint4*)&Bs[mrow * 40 + kq]     = b0;
            *(uint4*)&Bs[mrow * 40 + kq + 8] = b1;
        }
        __syncthreads();
        bf16x8 af[4], bfv[4];
#pragma unroll
        for (int i = 0; i < 4; i++) {
            af[i]  = *(const bf16x8*)&As[(wm + i * 16 + fm) * 40 + ko];
            bfv[i] = *(const bf16x8*)&Bs[(wn + i * 16 + fm) * 40 + ko];
        }
#pragma unroll
        for (int mi = 0; mi < 4; mi++)
#pragma unroll
            for (int ni = 0; ni < 4; ni++)
                acc[mi][ni] = __builtin_amdgcn_mfma_f32_16x16x32_bf16(
                    af[mi], bfv[ni], acc[mi][ni], 0, 0, 0);
    }

    float* op = Cpart + (size_t)sp * M * E_DIM;
#pragma unroll
    for (int mi = 0; mi < 4; mi++) {
#pragma unroll
        for (int r = 0; r < 4; r++) {
            int row = row0 + wm + mi * 16 + (lane >> 4) * 4 + r;
            if (row < M) {
#pragma unroll
                for (int ni = 0; ni < 4; ni++)
                    op[(size_t)row * E_DIM + wn + ni * 16 + fm] = acc[mi][ni][r];
            }
        }
    }
}

// ---------------------------------------------------------------------------
// Head: 128 triples/block. Gather pre-scaled bf16 rows of xs into LDS (bare
// 32B copies), MFMA vs Wp1T, fused hardshrink->dot(Wp2)->hardshrink epilogue.
// ---------------------------------------------------------------------------
__global__ __launch_bounds__(256) void head_bf16(const unsigned short* __restrict__ xs,
                                                 const int* __restrict__ tpl,
                                                 const unsigned short* __restrict__ Wp1T,
                                                 const float* __restrict__ bp1,
                                                 const float* __restrict__ Wp2,
                                                 const float* __restrict__ bp2,
                                                 float* __restrict__ outp) {
    __shared__ unsigned short As[128 * 40];
    __shared__ unsigned short Bs[128 * 40];
    __shared__ int   ridx[128][3];
    __shared__ float sred[2][128];

    const int tid = threadIdx.x;
    const int m0  = blockIdx.x * 128;

    for (int i = tid; i < 384; i += 256) {
        int m = i / 3, s = i - m * 3;
        int gm = m0 + m;
        int r = 0;
        if (gm < M_TPL) r = tpl[gm * 3 + s];
        ridx[m][s] = r;
    }

    const int mrow = tid >> 1;
    const int kq   = (tid & 1) * 16;
    const int lane = tid & 63;
    const int w  = tid >> 6;
    const int wm = (w & 1) * 64;
    const int wn = (w >> 1) * 64;
    const int fm = lane & 15;
    const int ko = (lane >> 4) * 8;

    const f32x4 zero = {0.f, 0.f, 0.f, 0.f};
    f32x4 acc[4][4];
#pragma unroll
    for (int i = 0; i < 4; i++)
#pragma unroll
        for (int j = 0; j < 4; j++) acc[i][j] = zero;

    for (int kt = 0; kt < 12; kt++) {
        __syncthreads();   // kt==0 also covers ridx staging
        // ---- A tile: gathered bf16 copy ----
        {
            const int seg  = kt >> 2;
            const int kcol = (kt & 3) * 32 + kq;
            int r = ridx[mrow][seg];
            const uint4* src = (const uint4*)(xs + (size_t)r * E_DIM + kcol);
            uint4 a0 = src[0];
            uint4 a1 = src[1];
            *(uint4*)&As[mrow * 40 + kq]     = a0;
            *(uint4*)&As[mrow * 40 + kq + 8] = a1;
        }
        // ---- B tile from Wp1T ----
        {
            const uint4* src = (const uint4*)(Wp1T + (size_t)mrow * 384 + kt * 32 + kq);
            uint4 b0 = src[0];
            uint4 b1 = src[1];
            *(uint4*)&Bs[mrow * 40 + kq]     = b0;
            *(uint4*)&Bs[mrow * 40 + kq + 8] = b1;
        }
        __syncthreads();
        bf16x8 af[4], bfv[4];
#pragma unroll
        for (int i = 0; i < 4; i++) {
            af[i]  = *(const bf16x8*)&As[(wm + i * 16 + fm) * 40 + ko];
            bfv[i] = *(const bf16x8*)&Bs[(wn + i * 16 + fm) * 40 + ko];
        }
#pragma unroll
        for (int mi = 0; mi < 4; mi++)
#pragma unroll
            for (int ni = 0; ni < 4; ni++)
                acc[mi][ni] = __builtin_amdgcn_mfma_f32_16x16x32_bf16(
                    af[mi], bfv[ni], acc[mi][ni], 0, 0, 0);
    }

    // ---- epilogue: u=HS(acc+bp1); s=sum_n u*Wp2[n]; out=HS(s+bp2) ----
    float bp1v[4], wp2v[4];
#pragma unroll
    for (int ni = 0; ni < 4; ni++) {
        int n = wn + ni * 16 + fm;
        bp1v[ni] = bp1[n];
        wp2v[ni] = Wp2[n];
    }
#pragma unroll
    for (int mi = 0; mi < 4; mi++) {
#pragma unroll
        for (int r = 0; r < 4; r++) {
            float p = 0.f;
#pragma unroll
            for (int ni = 0; ni < 4; ni++)
                p += hshrink(acc[mi][ni][r] + bp1v[ni]) * wp2v[ni];
            p += __shfl_xor(p, 1, 64);
            p += __shfl_xor(p, 2, 64);
            p += __shfl_xor(p, 4, 64);
            p += __shfl_xor(p, 8, 64);
            if (fm == 0)
                sred[wn >> 6][wm + mi * 16 + (lane >> 4) * 4 + r] = p;
        }
    }
    __syncthreads();
    if (tid < 128) {
        int gm = m0 + tid;
        if (gm < M_TPL)
            outp[gm] = hshrink(sred[0][tid] + sred[1][tid] + bp2[0]);
    }
}

// ---------------------------------------------------------------------------
extern "C" void kernel_launch(void* const* d_in, const int* in_sizes, int n_in,
                              void* d_out, int out_size, void* d_ws, size_t ws_size,
                              hipStream_t stream) {
    const float* drugF = (const float*)d_in[0];
    const float* A     = (const float*)d_in[1];
    const int*   tpl   = (const int*)d_in[2];
    const float* rsd   = (const float*)d_in[3];
    const float* W1    = (const float*)d_in[4];
    const float* b1    = (const float*)d_in[5];
    const float* W2    = (const float*)d_in[6];
    const float* b2    = (const float*)d_in[7];
    const float* embSe = (const float*)d_in[8];
    const float* Wl    = (const float*)d_in[9];
    const float* bl    = (const float*)d_in[10];
    const float* Wp1   = (const float*)d_in[11];
    const float* bp1   = (const float*)d_in[12];
    const float* Wp2   = (const float*)d_in[13];
    const float* bp2   = (const float*)d_in[14];
    float* outp = (float*)d_out;

    float* ws = (float*)d_ws;
    const size_t XSZ = (size_t)N_TOT * E_DIM;   // 896000 floats
    // fixed bf16 blocks: xT + W1T + Wp1T + xs
    const size_t fixedB = ((size_t)128 * KPAD + (size_t)128 * 1024 +
                           (size_t)128 * 384 + XSZ) * 2;
    const size_t a16B = (size_t)N_TOT * KPAD * 2;
    // choose split-K count and A16 availability by workspace capacity
    int SPL = 2;
    bool useA16 = false;
    {
        const int cands[3] = {8, 4, 2};
        for (int ci = 0; ci < 3; ci++) {
            int s = cands[ci];
            size_t base = XSZ * 4 * (size_t)(1 + s) + fixedB;
            if (ws_size >= base + a16B) { SPL = s; useA16 = true; break; }
            if (ws_size >= base)        { SPL = s; useA16 = false; break; }
        }
    }
    float* x     = ws;
    float* parts = ws + XSZ;
    unsigned short* xT   = (unsigned short*)(ws + XSZ * (size_t)(1 + SPL));
    unsigned short* W1T  = xT  + (size_t)128 * KPAD;
    unsigned short* Wp1T = W1T + (size_t)128 * 1024;
    unsigned short* xs   = Wp1T + (size_t)128 * 384;
    unsigned short* A16  = xs  + XSZ;

    // 0) weight conversions
    transpose_bf16<<<dim3(1024 / 64, 2), 256, 0, stream>>>(W1, W1T, F_SIZE, 1024);
    transpose_bf16<<<dim3(384 / 64, 2), 256, 0, stream>>>(Wp1, Wp1T, 384, 384);
    // 1) MLP layer 1 (bf16 MFMA split-K) + fused-reduce fp32 MLP layer 2
    gemm_bf16<0><<<dim3((N_D + 127) / 128, SPL), 256, 0, stream>>>(
        drugF, F_SIZE, nullptr, 0, W1T, 1024, parts, N_D, F_SIZE);
    gemm_small<<<dim3((N_D + 63) / 64), 256, 0, stream>>>(
        parts, SPL, (size_t)N_D * E_DIM, b1, W2, b2, x, N_D, 0);
    // 2) embSe rows
    emb_copy<<<dim3((N_SE * E_DIM / 4 + 255) / 256), 256, 0, stream>>>(embSe, x);
    // 3) two propagation layers: x = HS( (A@x) @ Wl[i] + bl[i] )
    for (int l = 0; l < 2; l++) {
        transpose_bf16<<<dim3(KPAD / 64, 2), 256, 0, stream>>>(x, xT, N_TOT, KPAD);
        if (useA16) {
            if (l == 0)
                gemm_bf16<1><<<dim3((N_TOT + 127) / 128, SPL), 256, 0, stream>>>(
                    A, N_TOT, A16, KPAD, xT, KPAD, parts, N_TOT, N_TOT);
            else
                gemm_bf16<2><<<dim3((N_TOT + 127) / 128, SPL), 256, 0, stream>>>(
                    nullptr, 0, A16, KPAD, xT, KPAD, parts, N_TOT, N_TOT);
        } else {
            gemm_bf16<0><<<dim3((N_TOT + 127) / 128, SPL), 256, 0, stream>>>(
                A, N_TOT, nullptr, 0, xT, KPAD, parts, N_TOT, N_TOT);
        }
        gemm_small<<<dim3((N_TOT + 63) / 64), 256, 0, stream>>>(
            parts, SPL, XSZ, nullptr,
            Wl + (size_t)l * E_DIM * E_DIM, bl + (size_t)l * E_DIM, x, N_TOT, 1);
    }
    // 4) pre-scaled bf16 gather source, then head
    scale_x_bf16<<<dim3((N_TOT * (E_DIM / 8) + 255) / 256), 256, 0, stream>>>(
        x, rsd, xs);
    head_bf16<<<dim3((M_TPL + 127) / 128), 256, 0, stream>>>(
        xs, tpl, Wp1T, bp1, Wp2, bp2, outp);
}

// Round 4
// 543.412 us; speedup vs baseline: 1.0784x; 1.0784x over previous
//
#include <hip/hip_runtime.h>
#include <hip/hip_bf16.h>

// Problem constants (from reference setup_inputs)
#define F_SIZE 1024
#define E_DIM  128
#define N_D    6000
#define N_SE   1000
#define N_TOT  7000
#define M_TPL  300000
#define LAMB   1e-6f
#define KPAD   7040   // N_TOT rounded up (xT leading dim)

typedef __bf16 bf16x8 __attribute__((ext_vector_type(8)));
typedef float  f32x4  __attribute__((ext_vector_type(4)));

__device__ __forceinline__ float hshrink(float v) {
    return fabsf(v) > LAMB ? v : 0.0f;
}

// RNE float -> bf16 bits (inputs are finite; no NaN handling needed)
__device__ __forceinline__ unsigned short f2bf(float f) {
    unsigned int u = __builtin_bit_cast(unsigned int, f);
    unsigned int r = u + 0x7fffu + ((u >> 16) & 1u);
    return (unsigned short)(r >> 16);
}

// Barrier that waits only LDS ops (lgkmcnt(0)) and does NOT drain vmcnt —
// keeps prefetched global loads in flight across the barrier.
// simm16: vmcnt=63 (bits 3:0 + 15:14), expcnt=7 (6:4), lgkmcnt=0 (11:8).
__device__ __forceinline__ void lds_barrier() {
    __builtin_amdgcn_s_waitcnt(0xC07F);
    __builtin_amdgcn_s_barrier();
}

// ---------------------------------------------------------------------------
// Pipelined bf16 MFMA split-K GEMM:
//   Cpart[sp][row][n] = sum_{k in chunk sp} A[row][k] * BT[n][k]
// A fp32 (cvt during staging), BT bf16 row-major [128][ldbt] (zero-padded).
// Tile: BM=64, BN=128, BK=32; 256 thr = 4 waves, each 32x64 via 2x4 MFMAs.
// Double-buffered LDS + VGPR prefetch, ONE lds_barrier per k-tile.
// LDS rows padded to 40 shorts (80 B) -> 2-way bank aliasing only (free).
// ---------------------------------------------------------------------------
__global__ __launch_bounds__(256) void gemm_pipe(const float* __restrict__ A, int lda,
                                                 const unsigned short* __restrict__ BT, int ldbt,
                                                 float* __restrict__ Cpart,
                                                 int M, int K) {
    __shared__ unsigned short As[2][64 * 40];
    __shared__ unsigned short Bs[2][128 * 40];

    const int tid = threadIdx.x;
    const int row0 = blockIdx.x * 64;
    const int sp = blockIdx.y, nsp = gridDim.y;
    const int KT = (K + 31) / 32;
    const int kt0 = (sp * KT) / nsp;
    const int kt1 = ((sp + 1) * KT) / nsp;

    // A staging: thread -> row=tid>>2 (0..63), k-chunk=(tid&3)*8 floats
    const int ar  = tid >> 2;
    const int akc = (tid & 3) * 8;
    const bool arok = (row0 + ar) < M;
    const float* aBase = A + (size_t)(row0 + ar) * lda + akc;

    // B staging: thread -> row=tid>>1 (0..127), 16 shorts at (tid&1)*16
    const int br  = tid >> 1;
    const int bkq = (tid & 1) * 16;
    const unsigned short* bBase = BT + (size_t)br * ldbt + bkq;

    const int lane = tid & 63;
    const int w  = tid >> 6;
    const int wm = (w & 1) * 32;
    const int wn = (w >> 1) * 64;
    const int fm = lane & 15;
    const int ko = (lane >> 4) * 8;

    const f32x4 zero = {0.f, 0.f, 0.f, 0.f};
    f32x4 acc[2][4];
#pragma unroll
    for (int i = 0; i < 2; i++)
#pragma unroll
        for (int j = 0; j < 4; j++) acc[i][j] = zero;

    float4 pa0, pa1;
    uint4  pb0, pb1;
    {   // prologue prefetch: tile kt0
        const int k0 = kt0 * 32;
        pa0 = pa1 = make_float4(0.f, 0.f, 0.f, 0.f);
        if (arok && (k0 + akc) < K) {          // K is a multiple of 8
            pa0 = *(const float4*)(aBase + k0);
            pa1 = *(const float4*)(aBase + k0 + 4);
        }
        const uint4* bsrc = (const uint4*)(bBase + k0);
        pb0 = bsrc[0];
        pb1 = bsrc[1];
    }

    int buf = 0;
    for (int kt = kt0; kt < kt1; kt++) {
        // ---- store prefetched regs into LDS[buf] ----
        {
            unsigned short us[8];
            us[0] = f2bf(pa0.x); us[1] = f2bf(pa0.y);
            us[2] = f2bf(pa0.z); us[3] = f2bf(pa0.w);
            us[4] = f2bf(pa1.x); us[5] = f2bf(pa1.y);
            us[6] = f2bf(pa1.z); us[7] = f2bf(pa1.w);
            *(uint4*)&As[buf][ar * 40 + akc] = *(uint4*)us;
            *(uint4*)&Bs[buf][br * 40 + bkq]     = pb0;
            *(uint4*)&Bs[buf][br * 40 + bkq + 8] = pb1;
        }
        // ---- issue next tile's global loads (stay in flight across barrier)
        if (kt + 1 < kt1) {
            const int k0 = (kt + 1) * 32;
            pa0 = pa1 = make_float4(0.f, 0.f, 0.f, 0.f);
            if (arok && (k0 + akc) < K) {
                pa0 = *(const float4*)(aBase + k0);
                pa1 = *(const float4*)(aBase + k0 + 4);
            }
            const uint4* bsrc = (const uint4*)(bBase + k0);
            pb0 = bsrc[0];
            pb1 = bsrc[1];
        }
        lds_barrier();
        // ---- compute on LDS[buf] ----
        bf16x8 af[2], bfv[4];
        af[0] = *(const bf16x8*)&As[buf][(wm + fm) * 40 + ko];
        af[1] = *(const bf16x8*)&As[buf][(wm + 16 + fm) * 40 + ko];
#pragma unroll
        for (int j = 0; j < 4; j++)
            bfv[j] = *(const bf16x8*)&Bs[buf][(wn + j * 16 + fm) * 40 + ko];
#pragma unroll
        for (int mi = 0; mi < 2; mi++)
#pragma unroll
            for (int ni = 0; ni < 4; ni++)
                acc[mi][ni] = __builtin_amdgcn_mfma_f32_16x16x32_bf16(
                    af[mi], bfv[ni], acc[mi][ni], 0, 0, 0);
        buf ^= 1;
    }

    float* op = Cpart + (size_t)sp * M * E_DIM;
#pragma unroll
    for (int mi = 0; mi < 2; mi++) {
#pragma unroll
        for (int r = 0; r < 4; r++) {
            int row = row0 + wm + mi * 16 + (lane >> 4) * 4 + r;
            if (row < M) {
#pragma unroll
                for (int ni = 0; ni < 4; ni++)
                    op[(size_t)row * E_DIM + wn + ni * 16 + fm] = acc[mi][ni][r];
            }
        }
    }
}

// ---------------------------------------------------------------------------
// Small GEMM (K=128), BM=16 for block-count: fuses the split-K reduction.
//   Ain[r][k] = pre( sum_s parts[s][r][k] )   pre: optional +preBias then relu
//   out[r][e] = act( Ain@W + bias )           act: 0=relu 1=hardshrink
// 256 thr: thread -> row=tid>>4, cols kc..kc+7. W streamed from L2 (broadcast).
// ---------------------------------------------------------------------------
__global__ __launch_bounds__(256) void gemm_small2(const float* __restrict__ parts,
                                                   int nparts, size_t partStride,
                                                   const float* __restrict__ preBias,
                                                   const float* __restrict__ W,
                                                   const float* __restrict__ bias,
                                                   float* __restrict__ outp,
                                                   int Mrows, int act) {
    __shared__ float Asum[16][132];
    const int tid = threadIdx.x;
    const int row0 = blockIdx.x * 16;
    const int r  = tid >> 4;
    const int kc = (tid & 15) * 8;
    const int grow = row0 + r;

    float4 s0 = make_float4(0.f, 0.f, 0.f, 0.f);
    float4 s1 = make_float4(0.f, 0.f, 0.f, 0.f);
    if (grow < Mrows) {
        for (int s = 0; s < nparts; s++) {
            const float* p = parts + (size_t)s * partStride + (size_t)grow * 128 + kc;
            float4 q0 = *(const float4*)p;
            float4 q1 = *(const float4*)(p + 4);
            s0.x += q0.x; s0.y += q0.y; s0.z += q0.z; s0.w += q0.w;
            s1.x += q1.x; s1.y += q1.y; s1.z += q1.z; s1.w += q1.w;
        }
        if (preBias != nullptr) {
            float4 pb0 = *(const float4*)(preBias + kc);
            float4 pb1 = *(const float4*)(preBias + kc + 4);
            s0.x = fmaxf(s0.x + pb0.x, 0.f); s0.y = fmaxf(s0.y + pb0.y, 0.f);
            s0.z = fmaxf(s0.z + pb0.z, 0.f); s0.w = fmaxf(s0.w + pb0.w, 0.f);
            s1.x = fmaxf(s1.x + pb1.x, 0.f); s1.y = fmaxf(s1.y + pb1.y, 0.f);
            s1.z = fmaxf(s1.z + pb1.z, 0.f); s1.w = fmaxf(s1.w + pb1.w, 0.f);
        }
    }
    *(float4*)&Asum[r][kc]     = s0;
    *(float4*)&Asum[r][kc + 4] = s1;
    __syncthreads();

    float acc[8];
#pragma unroll
    for (int j = 0; j < 8; j++) acc[j] = 0.f;
    const float* wp = W + kc;
#pragma unroll 4
    for (int k = 0; k < 128; k++) {
        float a = Asum[r][k];
        float4 w0 = *(const float4*)(wp + (size_t)k * 128);
        float4 w1 = *(const float4*)(wp + (size_t)k * 128 + 4);
        acc[0] += a * w0.x; acc[1] += a * w0.y;
        acc[2] += a * w0.z; acc[3] += a * w0.w;
        acc[4] += a * w1.x; acc[5] += a * w1.y;
        acc[6] += a * w1.z; acc[7] += a * w1.w;
    }
    if (grow < Mrows) {
        float4 bv0 = *(const float4*)(bias + kc);
        float4 bv1 = *(const float4*)(bias + kc + 4);
        float v[8];
        v[0] = acc[0] + bv0.x; v[1] = acc[1] + bv0.y;
        v[2] = acc[2] + bv0.z; v[3] = acc[3] + bv0.w;
        v[4] = acc[4] + bv1.x; v[5] = acc[5] + bv1.y;
        v[6] = acc[6] + bv1.z; v[7] = acc[7] + bv1.w;
#pragma unroll
        for (int j = 0; j < 8; j++)
            v[j] = (act == 0) ? fmaxf(v[j], 0.f) : hshrink(v[j]);
        float* op = outp + (size_t)grow * 128 + kc;
        *(float4*)op       = make_float4(v[0], v[1], v[2], v[3]);
        *(float4*)(op + 4) = make_float4(v[4], v[5], v[6], v[7]);
    }
}

// ---------------------------------------------------------------------------
__global__ void emb_copy(const float* __restrict__ embSe, float* __restrict__ x) {
    int i = blockIdx.x * blockDim.x + threadIdx.x;
    if (i < N_SE * E_DIM / 4)
        ((float4*)(x + (size_t)N_D * E_DIM))[i] = ((const float4*)embSe)[i];
}

// ---------------------------------------------------------------------------
// src [nrows][128] fp32 -> dst [128][kpad] bf16 (rows >= nrows zero-filled)
// grid: (kpad/64, 2)
// ---------------------------------------------------------------------------
__global__ __launch_bounds__(256) void transpose_bf16(const float* __restrict__ src,
                                                      unsigned short* __restrict__ dst,
                                                      int nrows, int kpad) {
    __shared__ float t[64][65];
    const int r0 = blockIdx.x * 64;
    const int c0 = blockIdx.y * 64;
    const int tid = threadIdx.x;
    {
        const int i  = tid >> 4;          // 0..15
        const int cq = (tid & 15) * 4;
#pragma unroll
        for (int j = 0; j < 4; j++) {
            int r = r0 + i + j * 16;
            float4 v = make_float4(0.f, 0.f, 0.f, 0.f);
            if (r < nrows) v = *(const float4*)(src + (size_t)r * E_DIM + c0 + cq);
            t[i + j * 16][cq + 0] = v.x;
            t[i + j * 16][cq + 1] = v.y;
            t[i + j * 16][cq + 2] = v.z;
            t[i + j * 16][cq + 3] = v.w;
        }
    }
    __syncthreads();
    {
        const int ci = tid >> 2;          // 0..63
        const int rq = (tid & 3) * 16;
        unsigned short us[16];
#pragma unroll
        for (int j = 0; j < 16; j++) us[j] = f2bf(t[rq + j][ci]);
        unsigned short* dp = dst + (size_t)(c0 + ci) * kpad + r0 + rq;
        *(uint4*)dp       = *(uint4*)&us[0];
        *(uint4*)(dp + 8) = *(uint4*)&us[8];
    }
}

// ---------------------------------------------------------------------------
// xs[r][e] = bf16( x[r][e] * rsd[r] )  — pre-scaled gather source for the head
// ---------------------------------------------------------------------------
__global__ __launch_bounds__(256) void scale_x_bf16(const float* __restrict__ x,
                                                    const float* __restrict__ rsd,
                                                    unsigned short* __restrict__ xs) {
    int t = blockIdx.x * 256 + threadIdx.x;    // one thread per 8 elements
    if (t < N_TOT * (E_DIM / 8)) {
        int r = t >> 4;
        int c = (t & 15) * 8;
        float sc = rsd[r];
        const float* sp = x + (size_t)r * E_DIM + c;
        float4 v0 = *(const float4*)sp;
        float4 v1 = *(const float4*)(sp + 4);
        unsigned short us[8];
        us[0] = f2bf(v0.x * sc); us[1] = f2bf(v0.y * sc);
        us[2] = f2bf(v0.z * sc); us[3] = f2bf(v0.w * sc);
        us[4] = f2bf(v1.x * sc); us[5] = f2bf(v1.y * sc);
        us[6] = f2bf(v1.z * sc); us[7] = f2bf(v1.w * sc);
        *(uint4*)(xs + (size_t)r * E_DIM + c) = *(uint4*)us;
    }
}

// ---------------------------------------------------------------------------
// Head, pipelined: 128 triples/block, gather pre-scaled bf16 xs rows + Wp1T
// tiles with VGPR prefetch + double-buffered LDS + single lds_barrier/tile.
// Epilogue: u=HS(acc+bp1); s=sum_n u*Wp2[n]; out=HS(s+bp2).
// ---------------------------------------------------------------------------
__global__ __launch_bounds__(256) void head_pipe(const unsigned short* __restrict__ xs,
                                                 const int* __restrict__ tpl,
                                                 const unsigned short* __restrict__ Wp1T,
                                                 const float* __restrict__ bp1,
                                                 const float* __restrict__ Wp2,
                                                 const float* __restrict__ bp2,
                                                 float* __restrict__ outp) {
    __shared__ unsigned short As[2][128 * 40];
    __shared__ unsigned short Bs[2][128 * 40];
    __shared__ int   ridx[128][3];
    __shared__ float sred[2][128];

    const int tid = threadIdx.x;
    const int m0  = blockIdx.x * 128;

    for (int i = tid; i < 384; i += 256) {
        int m = i / 3, s = i - m * 3;
        int gm = m0 + m;
        ridx[m][s] = (gm < M_TPL) ? tpl[gm * 3 + s] : 0;
    }
    __syncthreads();

    const int mrow = tid >> 1;
    const int kq   = (tid & 1) * 16;
    const int lane = tid & 63;
    const int w  = tid >> 6;
    const int wm = (w & 1) * 64;
    const int wn = (w >> 1) * 64;
    const int fm = lane & 15;
    const int ko = (lane >> 4) * 8;

    const f32x4 zero = {0.f, 0.f, 0.f, 0.f};
    f32x4 acc[4][4];
#pragma unroll
    for (int i = 0; i < 4; i++)
#pragma unroll
        for (int j = 0; j < 4; j++) acc[i][j] = zero;

    uint4 pa0, pa1, pb0, pb1;
    {   // prologue prefetch: tile 0 (seg 0, kcol = kq)
        int r = ridx[mrow][0];
        const uint4* asrc = (const uint4*)(xs + (size_t)r * E_DIM + kq);
        pa0 = asrc[0]; pa1 = asrc[1];
        const uint4* bsrc = (const uint4*)(Wp1T + (size_t)mrow * 384 + kq);
        pb0 = bsrc[0]; pb1 = bsrc[1];
    }

    int buf = 0;
    for (int kt = 0; kt < 12; kt++) {
        *(uint4*)&As[buf][mrow * 40 + kq]     = pa0;
        *(uint4*)&As[buf][mrow * 40 + kq + 8] = pa1;
        *(uint4*)&Bs[buf][mrow * 40 + kq]     = pb0;
        *(uint4*)&Bs[buf][mrow * 40 + kq + 8] = pb1;
        if (kt < 11) {
            const int nk  = kt + 1;
            const int seg = nk >> 2;
            const int kcol = (nk & 3) * 32 + kq;
            int r = ridx[mrow][seg];
            const uint4* asrc = (const uint4*)(xs + (size_t)r * E_DIM + kcol);
            pa0 = asrc[0]; pa1 = asrc[1];
            const uint4* bsrc = (const uint4*)(Wp1T + (size_t)mrow * 384 + nk * 32 + kq);
            pb0 = bsrc[0]; pb1 = bsrc[1];
        }
        lds_barrier();
        bf16x8 af[4], bfv[4];
#pragma unroll
        for (int i = 0; i < 4; i++) {
            af[i]  = *(const bf16x8*)&As[buf][(wm + i * 16 + fm) * 40 + ko];
            bfv[i] = *(const bf16x8*)&Bs[buf][(wn + i * 16 + fm) * 40 + ko];
        }
#pragma unroll
        for (int mi = 0; mi < 4; mi++)
#pragma unroll
            for (int ni = 0; ni < 4; ni++)
                acc[mi][ni] = __builtin_amdgcn_mfma_f32_16x16x32_bf16(
                    af[mi], bfv[ni], acc[mi][ni], 0, 0, 0);
        buf ^= 1;
    }

    float bp1v[4], wp2v[4];
#pragma unroll
    for (int ni = 0; ni < 4; ni++) {
        int n = wn + ni * 16 + fm;
        bp1v[ni] = bp1[n];
        wp2v[ni] = Wp2[n];
    }
#pragma unroll
    for (int mi = 0; mi < 4; mi++) {
#pragma unroll
        for (int r = 0; r < 4; r++) {
            float p = 0.f;
#pragma unroll
            for (int ni = 0; ni < 4; ni++)
                p += hshrink(acc[mi][ni][r] + bp1v[ni]) * wp2v[ni];
            p += __shfl_xor(p, 1, 64);
            p += __shfl_xor(p, 2, 64);
            p += __shfl_xor(p, 4, 64);
            p += __shfl_xor(p, 8, 64);
            if (fm == 0)
                sred[wn >> 6][wm + mi * 16 + (lane >> 4) * 4 + r] = p;
        }
    }
    __syncthreads();
    if (tid < 128) {
        int gm = m0 + tid;
        if (gm < M_TPL)
            outp[gm] = hshrink(sred[0][tid] + sred[1][tid] + bp2[0]);
    }
}

// ---------------------------------------------------------------------------
extern "C" void kernel_launch(void* const* d_in, const int* in_sizes, int n_in,
                              void* d_out, int out_size, void* d_ws, size_t ws_size,
                              hipStream_t stream) {
    const float* drugF = (const float*)d_in[0];
    const float* A     = (const float*)d_in[1];
    const int*   tpl   = (const int*)d_in[2];
    const float* rsd   = (const float*)d_in[3];
    const float* W1    = (const float*)d_in[4];
    const float* b1    = (const float*)d_in[5];
    const float* W2    = (const float*)d_in[6];
    const float* b2    = (const float*)d_in[7];
    const float* embSe = (const float*)d_in[8];
    const float* Wl    = (const float*)d_in[9];
    const float* bl    = (const float*)d_in[10];
    const float* Wp1   = (const float*)d_in[11];
    const float* bp1   = (const float*)d_in[12];
    const float* Wp2   = (const float*)d_in[13];
    const float* bp2   = (const float*)d_in[14];
    float* outp = (float*)d_out;

    float* ws = (float*)d_ws;
    const size_t XSZ = (size_t)N_TOT * E_DIM;   // 896000 floats
    // fixed bf16 blocks: xT + W1T + Wp1T + xs
    const size_t fixedB = ((size_t)128 * KPAD + (size_t)128 * 1024 +
                           (size_t)128 * 384 + XSZ) * 2;
    int SPL = 2;
    {
        const int cands[4] = {12, 8, 4, 2};
        for (int ci = 0; ci < 4; ci++) {
            int s = cands[ci];
            if (ws_size >= XSZ * 4 * (size_t)(1 + s) + fixedB) { SPL = s; break; }
        }
    }
    float* x     = ws;
    float* parts = ws + XSZ;
    unsigned short* xT   = (unsigned short*)(ws + XSZ * (size_t)(1 + SPL));
    unsigned short* W1T  = xT  + (size_t)128 * KPAD;
    unsigned short* Wp1T = W1T + (size_t)128 * 1024;
    unsigned short* xs   = Wp1T + (size_t)128 * 384;

    // 0) weight conversions
    transpose_bf16<<<dim3(1024 / 64, 2), 256, 0, stream>>>(W1, W1T, F_SIZE, 1024);
    transpose_bf16<<<dim3(384 / 64, 2), 256, 0, stream>>>(Wp1, Wp1T, 384, 384);
    // 1) MLP layer 1 (pipelined bf16 MFMA split-K) + fused-reduce MLP layer 2
    gemm_pipe<<<dim3((N_D + 63) / 64, SPL), 256, 0, stream>>>(
        drugF, F_SIZE, W1T, 1024, parts, N_D, F_SIZE);
    gemm_small2<<<dim3((N_D + 15) / 16), 256, 0, stream>>>(
        parts, SPL, (size_t)N_D * E_DIM, b1, W2, b2, x, N_D, 0);
    // 2) embSe rows
    emb_copy<<<dim3((N_SE * E_DIM / 4 + 255) / 256), 256, 0, stream>>>(embSe, x);
    // 3) two propagation layers: x = HS( (A@x) @ Wl[i] + bl[i] )
    for (int l = 0; l < 2; l++) {
        transpose_bf16<<<dim3(KPAD / 64, 2), 256, 0, stream>>>(x, xT, N_TOT, KPAD);
        gemm_pipe<<<dim3((N_TOT + 63) / 64, SPL), 256, 0, stream>>>(
            A, N_TOT, xT, KPAD, parts, N_TOT, N_TOT);
        gemm_small2<<<dim3((N_TOT + 15) / 16), 256, 0, stream>>>(
            parts, SPL, XSZ, nullptr,
            Wl + (size_t)l * E_DIM * E_DIM, bl + (size_t)l * E_DIM, x, N_TOT, 1);
    }
    // 4) pre-scaled bf16 gather source, then head
    scale_x_bf16<<<dim3((N_TOT * (E_DIM / 8) + 255) / 256), 256, 0, stream>>>(
        x, rsd, xs);
    head_pipe<<<dim3((M_TPL + 127) / 128), 256, 0, stream>>>(
        xs, tpl, Wp1T, bp1, Wp2, bp2, outp);
}